// Round 13
// baseline (1274.890 us; speedup 1.0000x reference)
//
#include <hip/hip_runtime.h>
#include <stdint.h>

#define T_ 4
#define B_ 32
#define C_ 512
#define N_ 256
#define NH_ 8
#define NB_ (N_ / 8)            // 32 bytes of spike bits per (t,b,c) row
#define BITS_BYTES_ ((size_t)(T_ * B_ * C_) * NB_)  // 2 MiB per spike tensor

typedef float f32x2 __attribute__((ext_vector_type(2)));

// ---- forced VOP3P packed-f32 helpers (rounding identical to scalar ops) ----
__device__ __forceinline__ f32x2 pk_mul_d(f32x2 a, f32x2 b) {
  f32x2 r;
  asm("v_pk_mul_f32 %0, %1, %2" : "=v"(r) : "v"(a), "v"(b));
  return r;
}
__device__ __forceinline__ f32x2 pk_mul_x(f32x2 a, f32x2 b) {
  f32x2 r;
  asm("v_pk_mul_f32 %0, %1, %2 op_sel:[0,1] op_sel_hi:[1,0]"
      : "=v"(r) : "v"(a), "v"(b));
  return r;
}
__device__ __forceinline__ void pk_add_acc(f32x2& acc, f32x2 p) {
  asm("v_pk_add_f32 %0, %0, %1" : "+v"(acc) : "v"(p));
}
__device__ __forceinline__ void pk_fma_d(f32x2& acc, f32x2 a, f32x2 b) {
  asm("v_pk_fma_f32 %0, %1, %2, %0" : "+v"(acc) : "v"(a), "v"(b));
}
__device__ __forceinline__ void pk_fma_x(f32x2& acc, f32x2 a, f32x2 b) {
  asm("v_pk_fma_f32 %0, %1, %2, %0 op_sel:[0,1,0] op_sel_hi:[1,0,1]"
      : "+v"(acc) : "v"(a), "v"(b));
}

// async 16B global -> LDS (dest = wave-uniform lds base + lane*16)
__device__ __forceinline__ void gload_lds16(const void* g, void* l) {
  __builtin_amdgcn_global_load_lds(
      (const __attribute__((address_space(1))) unsigned int*)g,
      (__attribute__((address_space(3))) unsigned int*)l, 16, 0, 0);
}

// ws layout: [0,3MB) wt[3][512][512] (q,k,v transposed: wt[c][o]=w[o][c]);
//            [3MB,9MB) bit-packed spikes qb,kb,vb (2MB each); [9MB,11MB) ab.

__global__ __launch_bounds__(256) void transpose_w(
    const float* __restrict__ wq, const float* __restrict__ wk,
    const float* __restrict__ wv, float* __restrict__ wt_all) {
  const float* src = (blockIdx.z == 0) ? wq : (blockIdx.z == 1) ? wk : wv;
  float* dst = wt_all + (size_t)blockIdx.z * C_ * C_;
  __shared__ float tile[32][33];
  int bx = blockIdx.x * 32, by = blockIdx.y * 32;
  int tx = threadIdx.x, ty = threadIdx.y;
#pragma unroll
  for (int i = ty; i < 32; i += 8) tile[i][tx] = src[(size_t)(by + i) * C_ + bx + tx];
  __syncthreads();
#pragma unroll
  for (int i = ty; i < 32; i += 8) dst[(size_t)(bx + i) * C_ + by + tx] = tile[tx][i];
}

// ---------------------------------------------------------------------------
// Stage A: conv1x1 + BN + LIF for q,k,v -- f32, sequential-c accumulation,
// NO FMA contraction (replicates numpy-f32 einsum/BN/LIF rounding exactly).
// 256 thr, 64x128 tile, 4x8/thread, split cols (conflict-free LDS).
// BK=32, BOTH tiles staged via global_load_lds (A from pre-transposed wt),
// double-buffered, ONE barrier per K-step: loads in flight across the whole
// compute phase (m97/T3 pattern). br folded into bx for XCD L2 sharing.
// ---------------------------------------------------------------------------
__global__ __launch_bounds__(256, 2) void qkv_gemm_lif(
    const float* __restrict__ x, const float* __restrict__ wt_all,
    const float* __restrict__ bnq, const float* __restrict__ bnk,
    const float* __restrict__ bnv,
    uint8_t* __restrict__ sbits, float* __restrict__ out1) {
#pragma clang fp contract(off)
  const int bx = blockIdx.x;
  const int br = bx >> 4;           // 0=q 1=k 2=v (stride-16 -> same-XCD trio)
  const int tile = bx & 15;
  const int b  = blockIdx.y;
  const int ot = tile >> 1, nt = tile & 1;
  const float* wt = wt_all + (size_t)br * C_ * C_;   // wt[c][o]
  const float* bn = (br == 0) ? bnq : (br == 1) ? bnk : bnv;
  uint8_t* sb = sbits + (size_t)br * BITS_BYTES_;

  const int tid = threadIdx.x;
  const int tx = tid & 15, ty = tid >> 4;
  const int o0 = ot * 64, n0 = nt * 128;

  __shared__ float As[2][32][64];    // As[buf][k][o] = wt[kc+k][o0+o]  (8 KB ea)
  __shared__ float Bs[2][32][128];   // Bs[buf][k][n] = x[kc+k][n0+n]   (16 KB ea)

  float inv[4], add[4];
#pragma unroll
  for (int i = 0; i < 4; ++i) {
    int o = o0 + ty * 4 + i;
    float g = bn[o], be = bn[C_ + o], mm = bn[2 * C_ + o], va = bn[3 * C_ + o];
    float iv = g / sqrtf(va + 1e-5f);   // correctly-rounded sqrt/div, as np
    inv[i] = iv;
    add[i] = be - mm * iv;              // mul rounds, sub rounds (no contract)
  }

  float vst[4][8];                      // membrane state
#pragma unroll
  for (int i = 0; i < 4; ++i)
#pragma unroll
    for (int j = 0; j < 8; ++j) vst[i][j] = 0.f;

  const int wv_ = tid >> 6;             // wave id 0..3
  const int lane = tid & 63;

  for (int t = 0; t < T_; ++t) {
    const float* xb = x + (size_t)(t * B_ + b) * (C_ * N_);

    // stage(buf, kc): 6 async gload_lds, lane-linear dests
    auto stage = [&](int buf, int kc) {
#pragma unroll
      for (int r = 0; r < 2; ++r) {     // A: 512 slots of 16B
        int slot0 = r * 256 + wv_ * 64;
        int slot = slot0 + lane;
        int row = slot >> 4, col = (slot & 15) * 4;
        gload_lds16(wt + (size_t)(kc + row) * C_ + o0 + col,
                    (char*)&As[buf][0][0] + (size_t)slot0 * 16);
      }
#pragma unroll
      for (int r = 0; r < 4; ++r) {     // B: 1024 slots of 16B
        int slot0 = r * 256 + wv_ * 64;
        int slot = slot0 + lane;
        int row = slot >> 5, col = (slot & 31) * 4;
        gload_lds16(xb + (size_t)(kc + row) * N_ + n0 + col,
                    (char*)&Bs[buf][0][0] + (size_t)slot0 * 16);
      }
    };

    f32x2 acc_d[2][4], acc_x[2][4];
#pragma unroll
    for (int ip = 0; ip < 2; ++ip)
#pragma unroll
      for (int jp = 0; jp < 4; ++jp) {
        acc_d[ip][jp] = (f32x2){0.f, 0.f};
        acc_x[ip][jp] = (f32x2){0.f, 0.f};
      }

    stage(0, 0);          // prologue (prev-t readers done: last barrier of t-1)
    __syncthreads();      // drain prologue loads

    for (int it = 0; it < 16; ++it) {   // 16 K-steps of 32
      const int cur = it & 1;
      if (it < 15) stage(cur ^ 1, (it + 1) * 32);  // fly during compute
#pragma unroll
      for (int k = 0; k < 32; ++k) {   // strictly ascending c
        float4 av4 = *(const float4*)(&As[cur][k][ty * 4]);
        float4 bq0 = *(const float4*)(&Bs[cur][k][tx * 4]);
        float4 bq1 = *(const float4*)(&Bs[cur][k][64 + tx * 4]);
        f32x2 a2[2] = {(f32x2){av4.x, av4.y}, (f32x2){av4.z, av4.w}};
        f32x2 b2[4] = {(f32x2){bq0.x, bq0.y}, (f32x2){bq0.z, bq0.w},
                       (f32x2){bq1.x, bq1.y}, (f32x2){bq1.z, bq1.w}};
#pragma unroll
        for (int ip = 0; ip < 2; ++ip)
#pragma unroll
          for (int jp = 0; jp < 4; ++jp) {
            f32x2 pd = pk_mul_d(a2[ip], b2[jp]);   // rounds each half
            f32x2 px = pk_mul_x(a2[ip], b2[jp]);
            pk_add_acc(acc_d[ip][jp], pd);          // rounds each half
            pk_add_acc(acc_x[ip][jp], px);
          }
      }
      __syncthreads();    // drains nxt gloads; cur free for it+2
    }

    {  // BN + LIF epilogue, f32, plain-op rounding; nibble-pack spike bytes
      size_t tb = (size_t)(t * B_ + b);
      unsigned nibsA = 0, nibsB = 0;   // 4 bits per row i
#pragma unroll
      for (int i = 0; i < 4; ++i) {
#pragma unroll
        for (int jj = 0; jj < 8; ++jj) {
          int ip = i >> 1, il = i & 1, jp = jj >> 1, jl = jj & 1;
          float a = (il == jl) ? acc_d[ip][jp][il] : acc_x[ip][jp][il];
          float y0 = a * inv[i];
          float y = y0 + add[i];
          float d = y - vst[i][jj];
          float vs = vst[i][jj] + d * 0.5f;  // v += (x - v)/TAU, TAU=2
          unsigned sp = (vs >= 1.0f) ? 1u : 0u;
          vst[i][jj] = sp ? 0.f : vs;
          if (jj < 4) nibsA |= sp << (4 * i + jj);
          else        nibsB |= sp << (4 * i + jj - 4);
        }
      }
      // pair lanes (tx even/odd) hold low/high nibbles of the same bytes
      unsigned oA = __shfl_xor(nibsA, 1);
      unsigned oB = __shfl_xor(nibsB, 1);
      int m = tx >> 1;
      if ((tx & 1) == 0) {  // byte m: cols m*8..+3 = self(A), +4..+7 = partner(A)
#pragma unroll
        for (int i = 0; i < 4; ++i) {
          int o = o0 + ty * 4 + i;
          unsigned byte_ = ((nibsA >> (4 * i)) & 0xF) | (((oA >> (4 * i)) & 0xF) << 4);
          sb[(tb * C_ + o) * NB_ + (n0 >> 3) + m] = (uint8_t)byte_;
        }
      } else {              // byte 8+m: cols 64+m*8..; low = partner(B), high = self(B)
#pragma unroll
        for (int i = 0; i < 4; ++i) {
          int o = o0 + ty * 4 + i;
          unsigned byte_ = ((oB >> (4 * i)) & 0xF) | (((nibsB >> (4 * i)) & 0xF) << 4);
          sb[(tb * C_ + o) * NB_ + (n0 >> 3) + 8 + m] = (uint8_t)byte_;
        }
      }
      if (br == 2) {  // v spikes -> output 1, [T,B,h,N,d] float32
#pragma unroll
        for (int i = 0; i < 4; ++i) {
          int o = o0 + ty * 4 + i;
          int h = o >> 6, dd = o & 63;
          size_t base = ((tb * NH_ + h) * (size_t)N_) * 64 + dd;
#pragma unroll
          for (int jj = 0; jj < 8; ++jj) {
            int n = n0 + ((jj < 4) ? (tx * 4 + jj) : (64 + tx * 4 + jj - 4));
            unsigned sp = (jj < 4) ? ((nibsA >> (4 * i + jj)) & 1u)
                                   : ((nibsB >> (4 * i + jj - 4)) & 1u);
            out1[base + (size_t)n * 64] = sp ? 1.0f : 0.0f;
          }
        }
      }
    }
  }
}

// ---------------------------------------------------------------------------
// Stage B: linear attention on binary spikes + attn LIF. Bit-exact vs np-f32:
// popcounts are integers <= 16384 (< 2^24, exact in f32, order-free) and the
// attn-LIF membrane stays on a dyadic grid with < 24 significant bits.
// ---------------------------------------------------------------------------
__global__ __launch_bounds__(512, 1) void attn_lif(
    const uint8_t* __restrict__ bits, uint8_t* __restrict__ abits) {
#pragma clang fp contract(off)
  const unsigned long long* qb = (const unsigned long long*)bits;
  const unsigned long long* kb = qb + BITS_BYTES_ / 8;
  const unsigned long long* vb = kb + BITS_BYTES_ / 8;
  unsigned long long* ap = (unsigned long long*)abits;

  const int h = blockIdx.x, b = blockIdx.y;
  const int tid = threadIdx.x;
  const int lane = tid & 63, wave = tid >> 6;
  const int nw = wave & 3, eh = wave >> 2;

  __shared__ unsigned long long kbl[64][4];
  __shared__ unsigned long long vbl[64][4];
  __shared__ float kvl[64][64];

  float state[32];
#pragma unroll
  for (int e = 0; e < 32; ++e) state[e] = 0.f;

  for (int t = 0; t < T_; ++t) {
    size_t row0 = (size_t)(t * B_ + b) * C_ + h * 64;
    {
      int i = tid & 255, c = i >> 2, w = i & 3;
      if (tid < 256) kbl[c][w] = kb[(row0 + c) * 4 + w];
      else           vbl[c][w] = vb[(row0 + c) * 4 + w];
    }
    __syncthreads();
    {  // kv[d][e] = sum_n k[n,d]*v[n,e]  (exact integers)
      int d = tid & 63, eb = (tid >> 6) * 8;
#pragma unroll
      for (int e2 = 0; e2 < 8; ++e2) {
        int e = eb + e2;
        int s = 0;
#pragma unroll
        for (int w = 0; w < 4; ++w) s += __popcll(kbl[d][w] & vbl[e][w]);
        kvl[d][e] = (float)s;
      }
    }
    __syncthreads();
    float acc[32];
#pragma unroll
    for (int e = 0; e < 32; ++e) acc[e] = 0.f;
    for (int d = 0; d < 64; ++d) {
      unsigned long long qw = qb[(row0 + d) * 4 + nw];
      float qf = (float)(unsigned)((qw >> lane) & 1ULL);
      const float* kr = &kvl[d][eh * 32];
#pragma unroll
      for (int e = 0; e < 32; ++e) acc[e] = acc[e] + qf * kr[e];
    }
    {  // attn LIF (v_th=0.5), exact dyadic; ballot-pack spikes
#pragma unroll
      for (int e2 = 0; e2 < 32; ++e2) {
        int e = eh * 32 + e2;
        float a = acc[e2] * 0.125f;
        float d0 = a - state[e2];
        float vs = state[e2] + d0 * 0.5f;
        int sp = (vs >= 0.5f) ? 1 : 0;
        state[e2] = sp ? 0.f : vs;
        unsigned long long m = __ballot(sp);
        if (lane == 0) ap[(row0 + e) * 4 + nw] = m;
      }
    }
    __syncthreads();
  }
}

// ---------------------------------------------------------------------------
// Stage C: proj conv1x1 (+bias) + BN + LIF -> output 0 (f32 spikes).
// B operand is {0,1} so w*x products are EXACT -> pk-FMA == mul+add bitwise.
// Double-buffered single-barrier K-loop (R9 form). Epilogue contract-off.
// ---------------------------------------------------------------------------
__global__ __launch_bounds__(256, 2) void proj_gemm_lif(
    const uint8_t* __restrict__ ab, const float* __restrict__ wp,
    const float* __restrict__ pb, const float* __restrict__ bnp,
    float* __restrict__ out0) {
  const int b = blockIdx.y;
  const int ot = blockIdx.x >> 1, nt = blockIdx.x & 1;
  const int tid = threadIdx.x;
  const int tx = tid & 15, ty = tid >> 4;
  const int o0 = ot * 64, n0 = nt * 128;

  __shared__ float As[2][16][64];
  __shared__ float Bs[2][16][128];

  float inv[4], add[4], bias[4];
  {
#pragma clang fp contract(off)
#pragma unroll
    for (int i = 0; i < 4; ++i) {
      int o = o0 + ty * 4 + i;
      float g = bnp[o], be = bnp[C_ + o], mm = bnp[2 * C_ + o], va = bnp[3 * C_ + o];
      float iv = g / sqrtf(va + 1e-5f);
      inv[i] = iv;
      add[i] = be - mm * iv;
      bias[i] = pb[o];
    }
  }

  float vst[4][8];
#pragma unroll
  for (int i = 0; i < 4; ++i)
#pragma unroll
    for (int j = 0; j < 8; ++j) vst[i][j] = 0.f;

  const int sa_o = tid & 63, sa_kq = (tid >> 6) * 4;
  const int br_ = tid >> 4, bq16 = tid & 15;   // B: k-row, byte index

  for (int t = 0; t < T_; ++t) {
    f32x2 acc_d[2][4], acc_x[2][4];
#pragma unroll
    for (int ip = 0; ip < 2; ++ip)
#pragma unroll
      for (int jp = 0; jp < 4; ++jp) {
        acc_d[ip][jp] = (f32x2){0.f, 0.f};
        acc_x[ip][jp] = (f32x2){0.f, 0.f};
      }
    size_t tb = (size_t)(t * B_ + b);

    {  // prologue: stage tile kc=0 into buf 0
      float4 a4 = *(const float4*)(wp + (size_t)(o0 + sa_o) * C_ + 0 + sa_kq);
      uint8_t by = ab[(tb * C_ + 0 + br_) * NB_ + (n0 >> 3) + bq16];
      __syncthreads();
      As[0][sa_kq + 0][sa_o] = a4.x; As[0][sa_kq + 1][sa_o] = a4.y;
      As[0][sa_kq + 2][sa_o] = a4.z; As[0][sa_kq + 3][sa_o] = a4.w;
      int nb = bq16 * 8;
#pragma unroll
      for (int j = 0; j < 8; ++j) Bs[0][br_][nb + j] = (float)((by >> j) & 1);
      __syncthreads();
    }

    for (int it = 0; it < 32; ++it) {
      const int cur = it & 1;
      float4 a4; uint8_t by = 0;
      if (it < 31) {
        int kc = (it + 1) * 16;
        a4 = *(const float4*)(wp + (size_t)(o0 + sa_o) * C_ + kc + sa_kq);
        by = ab[(tb * C_ + kc + br_) * NB_ + (n0 >> 3) + bq16];
      }
#pragma unroll
      for (int k = 0; k < 16; ++k) {
        float4 av4 = *(const float4*)(&As[cur][k][ty * 4]);
        float4 bq0 = *(const float4*)(&Bs[cur][k][tx * 4]);
        float4 bq1 = *(const float4*)(&Bs[cur][k][64 + tx * 4]);
        f32x2 a2[2] = {(f32x2){av4.x, av4.y}, (f32x2){av4.z, av4.w}};
        f32x2 b2[4] = {(f32x2){bq0.x, bq0.y}, (f32x2){bq0.z, bq0.w},
                       (f32x2){bq1.x, bq1.y}, (f32x2){bq1.z, bq1.w}};
#pragma unroll
        for (int ip = 0; ip < 2; ++ip)
#pragma unroll
          for (int jp = 0; jp < 4; ++jp) {
            pk_fma_d(acc_d[ip][jp], a2[ip], b2[jp]);  // exact prods: fma-safe
            pk_fma_x(acc_x[ip][jp], a2[ip], b2[jp]);
          }
      }
      if (it < 31) {
        const int nxt = cur ^ 1;
        As[nxt][sa_kq + 0][sa_o] = a4.x; As[nxt][sa_kq + 1][sa_o] = a4.y;
        As[nxt][sa_kq + 2][sa_o] = a4.z; As[nxt][sa_kq + 3][sa_o] = a4.w;
        int nb = bq16 * 8;
#pragma unroll
        for (int j = 0; j < 8; ++j) Bs[nxt][br_][nb + j] = (float)((by >> j) & 1);
        __syncthreads();
      }
    }

    {
#pragma clang fp contract(off)
#pragma unroll
      for (int i = 0; i < 4; ++i) {
        int o = o0 + ty * 4 + i;
        float4 r0, r1;
#pragma unroll
        for (int jj = 0; jj < 8; ++jj) {
          int ip = i >> 1, il = i & 1, jp = jj >> 1, jl = jj & 1;
          float a = (il == jl) ? acc_d[ip][jp][il] : acc_x[ip][jp][il];
          float y1 = a + bias[i];
          float y2 = y1 * inv[i];
          float y = y2 + add[i];
          float d0 = y - vst[i][jj];
          float vs = vst[i][jj] + d0 * 0.5f;
          int sp = (vs >= 1.0f) ? 1 : 0;
          vst[i][jj] = sp ? 0.f : vs;
          if (jj < 4) (&r0.x)[jj] = sp ? 1.0f : 0.0f;
          else        (&r1.x)[jj - 4] = sp ? 1.0f : 0.0f;
        }
        float* dst = out0 + (tb * C_ + o) * N_ + n0;
        *(float4*)(dst + tx * 4) = r0;
        *(float4*)(dst + 64 + tx * 4) = r1;
      }
    }
  }
}

// ---------------------------------------------------------------------------

extern "C" void kernel_launch(void* const* d_in, const int* in_sizes, int n_in,
                              void* d_out, int out_size, void* d_ws, size_t ws_size,
                              hipStream_t stream) {
  const float* x   = (const float*)d_in[0];
  const float* qw  = (const float*)d_in[2];
  const float* kw  = (const float*)d_in[3];
  const float* vw  = (const float*)d_in[4];
  const float* pw  = (const float*)d_in[5];
  const float* pbb = (const float*)d_in[6];
  const float* qbn = (const float*)d_in[7];
  const float* kbn = (const float*)d_in[8];
  const float* vbn = (const float*)d_in[9];
  const float* pbn = (const float*)d_in[10];

  float* wt = (float*)d_ws;                               // 3 MB transposed w
  uint8_t* bits  = (uint8_t*)d_ws + 3u * 1024u * 1024u;   // qb,kb,vb 2MB each
  uint8_t* abits = bits + 3 * BITS_BYTES_;                // ab 2MB

  float* out0 = (float*)d_out;                              // [T,B,C,N] f32
  float* out1 = out0 + (size_t)T_ * B_ * C_ * N_;           // [T,B,h,N,d] f32

  transpose_w<<<dim3(16, 16, 3), dim3(32, 8), 0, stream>>>(qw, kw, vw, wt);
  qkv_gemm_lif<<<dim3(48, 32), dim3(256), 0, stream>>>(
      x, wt, qbn, kbn, vbn, bits, out1);
  attn_lif<<<dim3(8, 32), dim3(512), 0, stream>>>(bits, abits);
  proj_gemm_lif<<<dim3(16, 32), dim3(256), 0, stream>>>(abits, pw, pbb, pbn,
                                                        out0);
}

// Round 14
// 1239.864 us; speedup vs baseline: 1.0282x; 1.0282x over previous
//
#include <hip/hip_runtime.h>
#include <stdint.h>

#define T_ 4
#define B_ 32
#define C_ 512
#define N_ 256
#define NH_ 8
#define NB_ (N_ / 8)            // 32 bytes of spike bits per (t,b,c) row
#define BITS_BYTES_ ((size_t)(T_ * B_ * C_) * NB_)  // 2 MiB per spike tensor

typedef float f32x2 __attribute__((ext_vector_type(2)));

// ---- forced VOP3P packed-f32 helpers (rounding identical to scalar ops) ----
__device__ __forceinline__ f32x2 pk_mul_d(f32x2 a, f32x2 b) {
  f32x2 r;
  asm("v_pk_mul_f32 %0, %1, %2" : "=v"(r) : "v"(a), "v"(b));
  return r;
}
__device__ __forceinline__ f32x2 pk_mul_x(f32x2 a, f32x2 b) {
  f32x2 r;
  asm("v_pk_mul_f32 %0, %1, %2 op_sel:[0,1] op_sel_hi:[1,0]"
      : "=v"(r) : "v"(a), "v"(b));
  return r;
}
__device__ __forceinline__ void pk_add_acc(f32x2& acc, f32x2 p) {
  asm("v_pk_add_f32 %0, %0, %1" : "+v"(acc) : "v"(p));
}
__device__ __forceinline__ void pk_fma_d(f32x2& acc, f32x2 a, f32x2 b) {
  asm("v_pk_fma_f32 %0, %1, %2, %0" : "+v"(acc) : "v"(a), "v"(b));
}
__device__ __forceinline__ void pk_fma_x(f32x2& acc, f32x2 a, f32x2 b) {
  asm("v_pk_fma_f32 %0, %1, %2, %0 op_sel:[0,1,0] op_sel_hi:[1,0,1]"
      : "+v"(acc) : "v"(a), "v"(b));
}

// async 16B global -> LDS (dest = wave-uniform lds base + lane*16)
__device__ __forceinline__ void gload_lds16(const void* g, void* l) {
  __builtin_amdgcn_global_load_lds(
      (const __attribute__((address_space(1))) unsigned int*)g,
      (__attribute__((address_space(3))) unsigned int*)l, 16, 0, 0);
}

// ws layout: [0,3MB) wt[3][512][512] (q,k,v transposed: wt[c][o]=w[o][c]);
//            [3MB,9MB) bit-packed spikes qb,kb,vb (2MB each); [9MB,11MB) ab.

__global__ __launch_bounds__(256) void transpose_w(
    const float* __restrict__ wq, const float* __restrict__ wk,
    const float* __restrict__ wv, float* __restrict__ wt_all) {
  const float* src = (blockIdx.z == 0) ? wq : (blockIdx.z == 1) ? wk : wv;
  float* dst = wt_all + (size_t)blockIdx.z * C_ * C_;
  __shared__ float tile[32][33];
  int bx = blockIdx.x * 32, by = blockIdx.y * 32;
  int tx = threadIdx.x, ty = threadIdx.y;
#pragma unroll
  for (int i = ty; i < 32; i += 8) tile[i][tx] = src[(size_t)(by + i) * C_ + bx + tx];
  __syncthreads();
#pragma unroll
  for (int i = ty; i < 32; i += 8) dst[(size_t)(bx + i) * C_ + by + tx] = tile[tx][i];
}

// ---------------------------------------------------------------------------
// Stage A: conv1x1 + BN + LIF for q,k,v -- f32, sequential-c accumulation,
// NO FMA contraction (replicates numpy-f32 einsum/BN/LIF rounding exactly).
// R12 shape (single-buffer BK=32, 24KB LDS, 6 blocks/CU) but staging is
// 100% async gload_lds for BOTH tiles (A from pre-transposed wt): zero
// staging VALU / VGPR traffic between the two barriers.
// ---------------------------------------------------------------------------
__global__ __launch_bounds__(256, 2) void qkv_gemm_lif(
    const float* __restrict__ x, const float* __restrict__ wt_all,
    const float* __restrict__ bnq, const float* __restrict__ bnk,
    const float* __restrict__ bnv,
    uint8_t* __restrict__ sbits, float* __restrict__ out1) {
#pragma clang fp contract(off)
  const int bx = blockIdx.x;
  const int br = bx >> 4;           // 0=q 1=k 2=v (stride-16 -> same-XCD trio)
  const int tile = bx & 15;
  const int b  = blockIdx.y;
  const int ot = tile >> 1, nt = tile & 1;
  const float* wt = wt_all + (size_t)br * C_ * C_;   // wt[c][o]
  const float* bn = (br == 0) ? bnq : (br == 1) ? bnk : bnv;
  uint8_t* sb = sbits + (size_t)br * BITS_BYTES_;

  const int tid = threadIdx.x;
  const int tx = tid & 15, ty = tid >> 4;
  const int o0 = ot * 64, n0 = nt * 128;

  __shared__ float As[32][64];    // As[k][o] = wt[kc+k][o0+o]   (8 KB)
  __shared__ float Bs[32][128];   // Bs[k][n] = x[kc+k][n0+n]    (16 KB)

  float inv[4], add[4];
#pragma unroll
  for (int i = 0; i < 4; ++i) {
    int o = o0 + ty * 4 + i;
    float g = bn[o], be = bn[C_ + o], mm = bn[2 * C_ + o], va = bn[3 * C_ + o];
    float iv = g / sqrtf(va + 1e-5f);   // correctly-rounded sqrt/div, as np
    inv[i] = iv;
    add[i] = be - mm * iv;              // mul rounds, sub rounds (no contract)
  }

  float vst[4][8];                      // membrane state
#pragma unroll
  for (int i = 0; i < 4; ++i)
#pragma unroll
    for (int j = 0; j < 8; ++j) vst[i][j] = 0.f;

  const int wv_ = tid >> 6;             // wave id 0..3
  const int lane = tid & 63;

  for (int t = 0; t < T_; ++t) {
    const float* xb = x + (size_t)(t * B_ + b) * (C_ * N_);
    f32x2 acc_d[2][4], acc_x[2][4];
#pragma unroll
    for (int ip = 0; ip < 2; ++ip)
#pragma unroll
      for (int jp = 0; jp < 4; ++jp) {
        acc_d[ip][jp] = (f32x2){0.f, 0.f};
        acc_x[ip][jp] = (f32x2){0.f, 0.f};
      }

    for (int kc = 0; kc < C_; kc += 32) {
      __syncthreads();   // all reads of previous tile (or prev t) complete
      // A: 512 16B slots; slot s -> k=s>>4, col=(s&15)*4 (linear in As)
#pragma unroll
      for (int r = 0; r < 2; ++r) {
        int slot0 = r * 256 + wv_ * 64;
        int slot = slot0 + lane;
        int row = slot >> 4, col = (slot & 15) * 4;
        gload_lds16(wt + (size_t)(kc + row) * C_ + o0 + col,
                    (char*)&As[0][0] + (size_t)slot0 * 16);
      }
      // B: 1024 16B slots; slot s -> k=s>>5, col=(s&31)*4 (linear in Bs)
#pragma unroll
      for (int r = 0; r < 4; ++r) {
        int slot0 = r * 256 + wv_ * 64;
        int slot = slot0 + lane;
        int row = slot >> 5, col = (slot & 31) * 4;
        gload_lds16(xb + (size_t)(kc + row) * N_ + n0 + col,
                    (char*)&Bs[0][0] + (size_t)slot0 * 16);
      }
      __syncthreads();   // drains gload_lds (vmcnt) -> tile visible
#pragma unroll
      for (int k = 0; k < 32; ++k) {   // strictly ascending c
        float4 av4 = *(const float4*)(&As[k][ty * 4]);
        float4 bq0 = *(const float4*)(&Bs[k][tx * 4]);
        float4 bq1 = *(const float4*)(&Bs[k][64 + tx * 4]);
        f32x2 a2[2] = {(f32x2){av4.x, av4.y}, (f32x2){av4.z, av4.w}};
        f32x2 b2[4] = {(f32x2){bq0.x, bq0.y}, (f32x2){bq0.z, bq0.w},
                       (f32x2){bq1.x, bq1.y}, (f32x2){bq1.z, bq1.w}};
#pragma unroll
        for (int ip = 0; ip < 2; ++ip)
#pragma unroll
          for (int jp = 0; jp < 4; ++jp) {
            f32x2 pd = pk_mul_d(a2[ip], b2[jp]);   // rounds each half
            f32x2 px = pk_mul_x(a2[ip], b2[jp]);
            pk_add_acc(acc_d[ip][jp], pd);          // rounds each half
            pk_add_acc(acc_x[ip][jp], px);
          }
      }
    }

    {  // BN + LIF epilogue, f32, plain-op rounding; nibble-pack spike bytes
      size_t tb = (size_t)(t * B_ + b);
      unsigned nibsA = 0, nibsB = 0;   // 4 bits per row i
#pragma unroll
      for (int i = 0; i < 4; ++i) {
#pragma unroll
        for (int jj = 0; jj < 8; ++jj) {
          int ip = i >> 1, il = i & 1, jp = jj >> 1, jl = jj & 1;
          float a = (il == jl) ? acc_d[ip][jp][il] : acc_x[ip][jp][il];
          float y0 = a * inv[i];
          float y = y0 + add[i];
          float d = y - vst[i][jj];
          float vs = vst[i][jj] + d * 0.5f;  // v += (x - v)/TAU, TAU=2
          unsigned sp = (vs >= 1.0f) ? 1u : 0u;
          vst[i][jj] = sp ? 0.f : vs;
          if (jj < 4) nibsA |= sp << (4 * i + jj);
          else        nibsB |= sp << (4 * i + jj - 4);
        }
      }
      // pair lanes (tx even/odd) hold low/high nibbles of the same bytes
      unsigned oA = __shfl_xor(nibsA, 1);
      unsigned oB = __shfl_xor(nibsB, 1);
      int m = tx >> 1;
      if ((tx & 1) == 0) {  // byte m: cols m*8..+3 = self(A), +4..+7 = partner(A)
#pragma unroll
        for (int i = 0; i < 4; ++i) {
          int o = o0 + ty * 4 + i;
          unsigned byte_ = ((nibsA >> (4 * i)) & 0xF) | (((oA >> (4 * i)) & 0xF) << 4);
          sb[(tb * C_ + o) * NB_ + (n0 >> 3) + m] = (uint8_t)byte_;
        }
      } else {              // byte 8+m: cols 64+m*8..; low = partner(B), high = self(B)
#pragma unroll
        for (int i = 0; i < 4; ++i) {
          int o = o0 + ty * 4 + i;
          unsigned byte_ = ((oB >> (4 * i)) & 0xF) | (((nibsB >> (4 * i)) & 0xF) << 4);
          sb[(tb * C_ + o) * NB_ + (n0 >> 3) + 8 + m] = (uint8_t)byte_;
        }
      }
      if (br == 2) {  // v spikes -> output 1, [T,B,h,N,d] float32
#pragma unroll
        for (int i = 0; i < 4; ++i) {
          int o = o0 + ty * 4 + i;
          int h = o >> 6, dd = o & 63;
          size_t base = ((tb * NH_ + h) * (size_t)N_) * 64 + dd;
#pragma unroll
          for (int jj = 0; jj < 8; ++jj) {
            int n = n0 + ((jj < 4) ? (tx * 4 + jj) : (64 + tx * 4 + jj - 4));
            unsigned sp = (jj < 4) ? ((nibsA >> (4 * i + jj)) & 1u)
                                   : ((nibsB >> (4 * i + jj - 4)) & 1u);
            out1[base + (size_t)n * 64] = sp ? 1.0f : 0.0f;
          }
        }
      }
    }
  }
}

// ---------------------------------------------------------------------------
// Stage B: linear attention on binary spikes + attn LIF. Bit-exact vs np-f32:
// popcounts are integers <= 16384 (< 2^24, exact in f32, order-free) and the
// attn-LIF membrane stays on a dyadic grid with < 24 significant bits.
// ---------------------------------------------------------------------------
__global__ __launch_bounds__(512, 1) void attn_lif(
    const uint8_t* __restrict__ bits, uint8_t* __restrict__ abits) {
#pragma clang fp contract(off)
  const unsigned long long* qb = (const unsigned long long*)bits;
  const unsigned long long* kb = qb + BITS_BYTES_ / 8;
  const unsigned long long* vb = kb + BITS_BYTES_ / 8;
  unsigned long long* ap = (unsigned long long*)abits;

  const int h = blockIdx.x, b = blockIdx.y;
  const int tid = threadIdx.x;
  const int lane = tid & 63, wave = tid >> 6;
  const int nw = wave & 3, eh = wave >> 2;

  __shared__ unsigned long long kbl[64][4];
  __shared__ unsigned long long vbl[64][4];
  __shared__ float kvl[64][64];

  float state[32];
#pragma unroll
  for (int e = 0; e < 32; ++e) state[e] = 0.f;

  for (int t = 0; t < T_; ++t) {
    size_t row0 = (size_t)(t * B_ + b) * C_ + h * 64;
    {
      int i = tid & 255, c = i >> 2, w = i & 3;
      if (tid < 256) kbl[c][w] = kb[(row0 + c) * 4 + w];
      else           vbl[c][w] = vb[(row0 + c) * 4 + w];
    }
    __syncthreads();
    {  // kv[d][e] = sum_n k[n,d]*v[n,e]  (exact integers)
      int d = tid & 63, eb = (tid >> 6) * 8;
#pragma unroll
      for (int e2 = 0; e2 < 8; ++e2) {
        int e = eb + e2;
        int s = 0;
#pragma unroll
        for (int w = 0; w < 4; ++w) s += __popcll(kbl[d][w] & vbl[e][w]);
        kvl[d][e] = (float)s;
      }
    }
    __syncthreads();
    float acc[32];
#pragma unroll
    for (int e = 0; e < 32; ++e) acc[e] = 0.f;
    for (int d = 0; d < 64; ++d) {
      unsigned long long qw = qb[(row0 + d) * 4 + nw];
      float qf = (float)(unsigned)((qw >> lane) & 1ULL);
      const float* kr = &kvl[d][eh * 32];
#pragma unroll
      for (int e = 0; e < 32; ++e) acc[e] = acc[e] + qf * kr[e];
    }
    {  // attn LIF (v_th=0.5), exact dyadic; ballot-pack spikes
#pragma unroll
      for (int e2 = 0; e2 < 32; ++e2) {
        int e = eh * 32 + e2;
        float a = acc[e2] * 0.125f;
        float d0 = a - state[e2];
        float vs = state[e2] + d0 * 0.5f;
        int sp = (vs >= 0.5f) ? 1 : 0;
        state[e2] = sp ? 0.f : vs;
        unsigned long long m = __ballot(sp);
        if (lane == 0) ap[(row0 + e) * 4 + nw] = m;
      }
    }
    __syncthreads();
  }
}

// ---------------------------------------------------------------------------
// Stage C: proj conv1x1 (+bias) + BN + LIF -> output 0 (f32 spikes).
// B operand is {0,1} so w*x products are EXACT -> pk-FMA == mul+add bitwise.
// Double-buffered single-barrier K-loop (R9 form). Epilogue contract-off.
// ---------------------------------------------------------------------------
__global__ __launch_bounds__(256, 2) void proj_gemm_lif(
    const uint8_t* __restrict__ ab, const float* __restrict__ wp,
    const float* __restrict__ pb, const float* __restrict__ bnp,
    float* __restrict__ out0) {
  const int b = blockIdx.y;
  const int ot = blockIdx.x >> 1, nt = blockIdx.x & 1;
  const int tid = threadIdx.x;
  const int tx = tid & 15, ty = tid >> 4;
  const int o0 = ot * 64, n0 = nt * 128;

  __shared__ float As[2][16][64];
  __shared__ float Bs[2][16][128];

  float inv[4], add[4], bias[4];
  {
#pragma clang fp contract(off)
#pragma unroll
    for (int i = 0; i < 4; ++i) {
      int o = o0 + ty * 4 + i;
      float g = bnp[o], be = bnp[C_ + o], mm = bnp[2 * C_ + o], va = bnp[3 * C_ + o];
      float iv = g / sqrtf(va + 1e-5f);
      inv[i] = iv;
      add[i] = be - mm * iv;
      bias[i] = pb[o];
    }
  }

  float vst[4][8];
#pragma unroll
  for (int i = 0; i < 4; ++i)
#pragma unroll
    for (int j = 0; j < 8; ++j) vst[i][j] = 0.f;

  const int sa_o = tid & 63, sa_kq = (tid >> 6) * 4;
  const int br_ = tid >> 4, bq16 = tid & 15;   // B: k-row, byte index

  for (int t = 0; t < T_; ++t) {
    f32x2 acc_d[2][4], acc_x[2][4];
#pragma unroll
    for (int ip = 0; ip < 2; ++ip)
#pragma unroll
      for (int jp = 0; jp < 4; ++jp) {
        acc_d[ip][jp] = (f32x2){0.f, 0.f};
        acc_x[ip][jp] = (f32x2){0.f, 0.f};
      }
    size_t tb = (size_t)(t * B_ + b);

    {  // prologue: stage tile kc=0 into buf 0
      float4 a4 = *(const float4*)(wp + (size_t)(o0 + sa_o) * C_ + 0 + sa_kq);
      uint8_t by = ab[(tb * C_ + 0 + br_) * NB_ + (n0 >> 3) + bq16];
      __syncthreads();
      As[0][sa_kq + 0][sa_o] = a4.x; As[0][sa_kq + 1][sa_o] = a4.y;
      As[0][sa_kq + 2][sa_o] = a4.z; As[0][sa_kq + 3][sa_o] = a4.w;
      int nb = bq16 * 8;
#pragma unroll
      for (int j = 0; j < 8; ++j) Bs[0][br_][nb + j] = (float)((by >> j) & 1);
      __syncthreads();
    }

    for (int it = 0; it < 32; ++it) {
      const int cur = it & 1;
      float4 a4; uint8_t by = 0;
      if (it < 31) {
        int kc = (it + 1) * 16;
        a4 = *(const float4*)(wp + (size_t)(o0 + sa_o) * C_ + kc + sa_kq);
        by = ab[(tb * C_ + kc + br_) * NB_ + (n0 >> 3) + bq16];
      }
#pragma unroll
      for (int k = 0; k < 16; ++k) {
        float4 av4 = *(const float4*)(&As[cur][k][ty * 4]);
        float4 bq0 = *(const float4*)(&Bs[cur][k][tx * 4]);
        float4 bq1 = *(const float4*)(&Bs[cur][k][64 + tx * 4]);
        f32x2 a2[2] = {(f32x2){av4.x, av4.y}, (f32x2){av4.z, av4.w}};
        f32x2 b2[4] = {(f32x2){bq0.x, bq0.y}, (f32x2){bq0.z, bq0.w},
                       (f32x2){bq1.x, bq1.y}, (f32x2){bq1.z, bq1.w}};
#pragma unroll
        for (int ip = 0; ip < 2; ++ip)
#pragma unroll
          for (int jp = 0; jp < 4; ++jp) {
            pk_fma_d(acc_d[ip][jp], a2[ip], b2[jp]);  // exact prods: fma-safe
            pk_fma_x(acc_x[ip][jp], a2[ip], b2[jp]);
          }
      }
      if (it < 31) {
        const int nxt = cur ^ 1;
        As[nxt][sa_kq + 0][sa_o] = a4.x; As[nxt][sa_kq + 1][sa_o] = a4.y;
        As[nxt][sa_kq + 2][sa_o] = a4.z; As[nxt][sa_kq + 3][sa_o] = a4.w;
        int nb = bq16 * 8;
#pragma unroll
        for (int j = 0; j < 8; ++j) Bs[nxt][br_][nb + j] = (float)((by >> j) & 1);
        __syncthreads();
      }
    }

    {
#pragma clang fp contract(off)
#pragma unroll
      for (int i = 0; i < 4; ++i) {
        int o = o0 + ty * 4 + i;
        float4 r0, r1;
#pragma unroll
        for (int jj = 0; jj < 8; ++jj) {
          int ip = i >> 1, il = i & 1, jp = jj >> 1, jl = jj & 1;
          float a = (il == jl) ? acc_d[ip][jp][il] : acc_x[ip][jp][il];
          float y1 = a + bias[i];
          float y2 = y1 * inv[i];
          float y = y2 + add[i];
          float d0 = y - vst[i][jj];
          float vs = vst[i][jj] + d0 * 0.5f;
          int sp = (vs >= 1.0f) ? 1 : 0;
          vst[i][jj] = sp ? 0.f : vs;
          if (jj < 4) (&r0.x)[jj] = sp ? 1.0f : 0.0f;
          else        (&r1.x)[jj - 4] = sp ? 1.0f : 0.0f;
        }
        float* dst = out0 + (tb * C_ + o) * N_ + n0;
        *(float4*)(dst + tx * 4) = r0;
        *(float4*)(dst + 64 + tx * 4) = r1;
      }
    }
  }
}

// ---------------------------------------------------------------------------

extern "C" void kernel_launch(void* const* d_in, const int* in_sizes, int n_in,
                              void* d_out, int out_size, void* d_ws, size_t ws_size,
                              hipStream_t stream) {
  const float* x   = (const float*)d_in[0];
  const float* qw  = (const float*)d_in[2];
  const float* kw  = (const float*)d_in[3];
  const float* vw  = (const float*)d_in[4];
  const float* pw  = (const float*)d_in[5];
  const float* pbb = (const float*)d_in[6];
  const float* qbn = (const float*)d_in[7];
  const float* kbn = (const float*)d_in[8];
  const float* vbn = (const float*)d_in[9];
  const float* pbn = (const float*)d_in[10];

  float* wt = (float*)d_ws;                               // 3 MB transposed w
  uint8_t* bits  = (uint8_t*)d_ws + 3u * 1024u * 1024u;   // qb,kb,vb 2MB each
  uint8_t* abits = bits + 3 * BITS_BYTES_;                // ab 2MB

  float* out0 = (float*)d_out;                              // [T,B,C,N] f32
  float* out1 = out0 + (size_t)T_ * B_ * C_ * N_;           // [T,B,h,N,d] f32

  transpose_w<<<dim3(16, 16, 3), dim3(32, 8), 0, stream>>>(qw, kw, vw, wt);
  qkv_gemm_lif<<<dim3(48, 32), dim3(256), 0, stream>>>(
      x, wt, qbn, kbn, vbn, bits, out1);
  attn_lif<<<dim3(8, 32), dim3(512), 0, stream>>>(bits, abits);
  proj_gemm_lif<<<dim3(16, 32), dim3(256), 0, stream>>>(abits, pw, pbb, pbn,
                                                        out0);
}